// Round 4
// baseline (64.373 us; speedup 1.0000x reference)
//
#include <hip/hip_runtime.h>
#include <math.h>

// Problem constants (match reference)
#define B_ 32
#define T_ 8192
#define C_ 64
#define S_ 256           // t-chunks per batch row
#define L_ 32            // t per chunk (one 32-bit ballot word)
#define EPS_ 1e-8f
#define SIGMA_MIN_ 1e-4f

// Workspace layout (float offsets); chunks = B_*S_ = 8192
#define SUM_OFF 0                        // 8192*64 = 524288
#define SQ_OFF  524288
#define MS_OFF  1048576
#define GAP_OFF 1572864                  // 8192 int4 = 32768 ints
#define MU_OFF  1605632                  // B_*C_ = 2048
#define INV_OFF 1607680                  // 2048
// total = 1609728 floats ~= 6.4 MiB

__device__ inline float4 f4add(float4 a, float4 b) {
    return make_float4(a.x + b.x, a.y + b.y, a.z + b.z, a.w + b.w);
}
__device__ inline float4 f4shfl_xor(float4 v, int m) {
    float4 r;
    r.x = __shfl_xor(v.x, m);
    r.y = __shfl_xor(v.y, m);
    r.z = __shfl_xor(v.z, m);
    r.w = __shfl_xor(v.w, m);
    return r;
}
// ordered merge of run-tuples: acc(l) then r
__device__ inline void merge_lr(int l_pre, int l_suf, int l_best, int l_len,
                                int r_pre, int r_suf, int r_best, int r_len,
                                int& pre, int& suf, int& best, int& len) {
    best = max(max(l_best, r_best), l_suf + r_pre);
    pre  = (l_pre == l_len) ? l_len + r_pre : l_pre;
    suf  = (r_suf == r_len) ? r_len + l_suf : r_suf;
    len  = l_len + r_len;
}

// ---------------- Kernel 1: k3-shaped streaming partial stats ----------------
// One x-float4 + one mask-float4 per thread, shallow reduction, one barrier.
__global__ __launch_bounds__(512) void k1_stats(const float* __restrict__ x,
                                                const float* __restrict__ mask,
                                                float* __restrict__ ws) {
    const int bid = blockIdx.x;            // 0 .. 8191  (b*S_ + s)
    const int b   = bid >> 8;
    const int s   = bid & (S_ - 1);
    const int tid = threadIdx.x;           // 0..511
    const int cq  = tid & 15;              // channel quad
    const int tr  = tid >> 4;              // 0..31 (t within chunk)
    const int wv  = tid >> 6;              // wave 0..7

    // identical addressing to k3: one float4 of x, one of mask
    const long gi = ((long)b * T_ + (long)s * L_ + tr) * 16 + cq;
    const float4 xv = ((const float4*)x)[gi];
    const float4 mv = ((const float4*)mask)[gi];

    __shared__ unsigned char misbyte[L_];
    if (cq == 0) misbyte[tr] = (mv.x < 0.5f) ? 1 : 0;

    float4 s1 = xv;
    float4 s2 = make_float4(xv.x * xv.x, xv.y * xv.y, xv.z * xv.z, xv.w * xv.w);
    float4 sm = mv;

    // reduce the 4 t-rows of this wave (lane bits 4..5)
    s1 = f4add(s1, f4shfl_xor(s1, 16)); s1 = f4add(s1, f4shfl_xor(s1, 32));
    s2 = f4add(s2, f4shfl_xor(s2, 16)); s2 = f4add(s2, f4shfl_xor(s2, 32));
    sm = f4add(sm, f4shfl_xor(sm, 16)); sm = f4add(sm, f4shfl_xor(sm, 32));

    __shared__ float4 shA[8][16];
    __shared__ float4 shB[8][16];
    __shared__ float4 shC[8][16];
    if ((tid & 63) < 16) { shA[wv][cq] = s1; shB[wv][cq] = s2; shC[wv][cq] = sm; }
    __syncthreads();

    if (tid < 16) {
        float4 a = f4add(f4add(f4add(shA[0][tid], shA[1][tid]), f4add(shA[2][tid], shA[3][tid])),
                         f4add(f4add(shA[4][tid], shA[5][tid]), f4add(shA[6][tid], shA[7][tid])));
        float4 c = f4add(f4add(f4add(shB[0][tid], shB[1][tid]), f4add(shB[2][tid], shB[3][tid])),
                         f4add(f4add(shB[4][tid], shB[5][tid]), f4add(shB[6][tid], shB[7][tid])));
        float4 e = f4add(f4add(f4add(shC[0][tid], shC[1][tid]), f4add(shC[2][tid], shC[3][tid])),
                         f4add(f4add(shC[4][tid], shC[5][tid]), f4add(shC[6][tid], shC[7][tid])));
        ((float4*)(ws + SUM_OFF))[bid * 16 + tid] = a;
        ((float4*)(ws + SQ_OFF ))[bid * 16 + tid] = c;
        ((float4*)(ws + MS_OFF ))[bid * 16 + tid] = e;
    }

    // gap tuple for this 32-t chunk from one ballot
    if (tid < 32) {
        const int miss = misbyte[tid];
        unsigned long long bal = __ballot(miss != 0);   // lanes 32-63 inactive -> 0
        if (tid == 0) {
            unsigned int w = (unsigned int)bal;
            int pre, suf, best;
            if (w == 0xFFFFFFFFu) {
                pre = 32; suf = 32; best = 32;
            } else {
                pre = __builtin_ctz(~w);          // leading (t=0 side) missing run
                suf = __builtin_clz(~w);          // trailing (t=31 side) missing run
                unsigned int tmp = w; best = 0;
                while (tmp) { tmp &= (tmp << 1); ++best; }
            }
            ((int4*)((int*)(ws + GAP_OFF)))[bid] = make_int4(pre, suf, best, L_);
        }
    }
}

// ---------------- Kernel 2: combine partials -> per-(b,c) mu, 1/sigma --------
__global__ __launch_bounds__(256) void k2_params(const int*   __restrict__ phase_id,
                                                 const float* __restrict__ anchor_mu,
                                                 const float* __restrict__ anchor_ls,
                                                 const float* __restrict__ tau0_raw,
                                                 const float* __restrict__ tau1_raw,
                                                 float* __restrict__ ws) {
    const int b   = blockIdx.x;
    const int tid = threadIdx.x;
    const int q   = tid & 15;        // channel quad
    const int p   = tid >> 4;        // row group 0..15

    // coalesced partial-sum accumulation: 16 rows per thread, float4
    float4 a1 = make_float4(0.f, 0.f, 0.f, 0.f);
    float4 a2 = make_float4(0.f, 0.f, 0.f, 0.f);
    float4 am = make_float4(0.f, 0.f, 0.f, 0.f);
#pragma unroll
    for (int i = 0; i < 16; ++i) {
        const int idx = (b * S_ + (p + i * 16)) * 16 + q;
        a1 = f4add(a1, ((const float4*)(ws + SUM_OFF))[idx]);
        a2 = f4add(a2, ((const float4*)(ws + SQ_OFF ))[idx]);
        am = f4add(am, ((const float4*)(ws + MS_OFF ))[idx]);
    }

    __shared__ float shf[3][16][64];
    *(float4*)&shf[0][p][q * 4] = a1;
    *(float4*)&shf[1][p][q * 4] = a2;
    *(float4*)&shf[2][p][q * 4] = am;
    __syncthreads();

    if (tid < 64) {
        // ---- gap merge: 256 tuples, 4 serial per lane + 6-step butterfly ----
        const int4* gp = (const int4*)((const int*)(ws + GAP_OFF)) + b * S_;
        int pre, suf, best, len;
        {
            int4 t0 = gp[tid * 4];
            pre = t0.x; suf = t0.y; best = t0.z; len = t0.w;
        }
#pragma unroll
        for (int k = 1; k < 4; ++k) {
            int4 r = gp[tid * 4 + k];
            merge_lr(pre, suf, best, len, r.x, r.y, r.z, r.w, pre, suf, best, len);
        }
#pragma unroll
        for (int m = 1; m < 64; m <<= 1) {
            int ppre = __shfl_xor(pre, m);
            int psuf = __shfl_xor(suf, m);
            int pbest = __shfl_xor(best, m);
            int plen = __shfl_xor(len, m);
            if (tid & m)   // partner is LEFT
                merge_lr(ppre, psuf, pbest, plen, pre, suf, best, len,
                         pre, suf, best, len);
            else           // partner is RIGHT
                merge_lr(pre, suf, best, len, ppre, psuf, pbest, plen,
                         pre, suf, best, len);
        }
        const float gap = (float)best / (float)T_;

        // ---- per-channel finalize ----
        const int c = tid;
        float sum = 0.f, sq = 0.f, ms = 0.f;
#pragma unroll
        for (int pp = 0; pp < 16; ++pp) {
            sum += shf[0][pp][c];
            sq  += shf[1][pp][c];
            ms  += shf[2][pp][c];
        }

        const float msc    = fmaxf(ms, EPS_);
        const float mu_obs = sum / msc;
        float var = (sq - 2.f * mu_obs * sum + mu_obs * mu_obs * ms) / msc;
        var = fmaxf(var, 0.f);
        const float sigma_obs = sqrtf(var + EPS_);
        const float coverage  = ms / (float)T_;

        const float t0 = log1pf(expf(tau0_raw[0]));   // softplus
        const float t1 = log1pf(expf(tau1_raw[0]));
        const float w  = coverage / (coverage + t0 + t1 * gap + EPS_);

        const int   pid    = phase_id[b];
        const float mu_ref = anchor_mu[pid * C_ + c];
        const float ls_ref = anchor_ls[pid * C_ + c];

        const float mu = w * mu_obs + (1.f - w) * mu_ref;
        const float ls = w * logf(sigma_obs + EPS_) + (1.f - w) * ls_ref;
        const float sigma = fmaxf(expf(ls), SIGMA_MIN_);

        ws[MU_OFF  + b * C_ + c] = mu;
        ws[INV_OFF + b * C_ + c] = 1.f / sigma;
    }
}

// ---------------- Kernel 3: elementwise normalize ---------------------------
__global__ __launch_bounds__(256) void k3_norm(const float* __restrict__ x,
                                               const float* __restrict__ mask,
                                               const float* __restrict__ token,
                                               const float* __restrict__ ws,
                                               float* __restrict__ out) {
    const int gid = blockIdx.x * 256 + threadIdx.x;   // float4 index
    const float4* x4 = (const float4*)x;
    const float4* m4 = (const float4*)mask;
    const float4* mu4  = (const float4*)(ws + MU_OFF);
    const float4* inv4 = (const float4*)(ws + INV_OFF);
    const float4* tk4  = (const float4*)token;

    const int b = gid >> 17;            // T_*C_/4 = 131072 float4 per b
    const int p = b * 16 + (gid & 15);  // (b, channel-quad)

    float4 xv = x4[gid];
    float4 mv = m4[gid];
    float4 mu = mu4[p];
    float4 iv = inv4[p];
    float4 tk = tk4[gid & 15];

    float4 o;
    o.x = mv.x * ((xv.x - mu.x) * iv.x) + (1.f - mv.x) * tk.x;
    o.y = mv.y * ((xv.y - mu.y) * iv.y) + (1.f - mv.y) * tk.y;
    o.z = mv.z * ((xv.z - mu.z) * iv.z) + (1.f - mv.z) * tk.z;
    o.w = mv.w * ((xv.w - mu.w) * iv.w) + (1.f - mv.w) * tk.w;

    ((float4*)out)[gid] = o;
}

extern "C" void kernel_launch(void* const* d_in, const int* in_sizes, int n_in,
                              void* d_out, int out_size, void* d_ws, size_t ws_size,
                              hipStream_t stream) {
    const float* x    = (const float*)d_in[0];
    const float* mask = (const float*)d_in[1];
    const int*   pid  = (const int*)  d_in[2];
    const float* amu  = (const float*)d_in[3];
    const float* als  = (const float*)d_in[4];
    const float* t0   = (const float*)d_in[5];
    const float* t1   = (const float*)d_in[6];
    const float* tok  = (const float*)d_in[7];
    float* out = (float*)d_out;
    float* ws  = (float*)d_ws;

    k1_stats<<<B_ * S_, 512, 0, stream>>>(x, mask, ws);
    k2_params<<<B_, 256, 0, stream>>>(pid, amu, als, t0, t1, ws);
    const int n4 = B_ * T_ * C_ / 4;          // 4194304 float4s
    k3_norm<<<n4 / 256, 256, 0, stream>>>(x, mask, tok, ws, out);
}